// Round 1
// baseline (382.262 us; speedup 1.0000x reference)
//
#include <hip/hip_runtime.h>
#include <hip/hip_bf16.h>

// Problem constants
#define BATCH   2048
#define IN_CH   12
#define UPLAG   2048
#define STEP    4
#define FEAT    512              // UPLAG/STEP
#define DIN     6144             // IN_CH*FEAT
#define HIDDEN  1024
#define OUTPUT  256

typedef __bf16 bf16x8 __attribute__((ext_vector_type(8)));
typedef float  f32x4  __attribute__((ext_vector_type(4)));

__device__ __forceinline__ unsigned short f2bf(float f) {
  unsigned int u = __builtin_bit_cast(unsigned int, f);
  unsigned int r = (u + 0x7fffu + ((u >> 16) & 1u)) >> 16;   // RNE
  return (unsigned short)r;
}

__device__ __forceinline__ void async_copy16(const unsigned short* g, unsigned short* l) {
  __builtin_amdgcn_global_load_lds(
      (const __attribute__((address_space(1))) unsigned int*)g,
      (__attribute__((address_space(3))) unsigned int*)l, 16, 0, 0);
}

// ---------------------------------------------------------------------------
// Kernel 1: per-channel stride-4 conv + bias, cast to bf16.
// x: [B, C, L] fp32 viewed as float4 [B*C*F]; out flat: [B, C*F] bf16
// flat index == float4 index (gid), so this is a pure streaming pass.
// ---------------------------------------------------------------------------
__global__ __launch_bounds__(256) void conv_cast_kernel(
    const float* __restrict__ x, const float* __restrict__ W1,
    const float* __restrict__ b1, unsigned short* __restrict__ out)
{
  int gid = blockIdx.x * 256 + threadIdx.x;
  const int total = BATCH * DIN;
  if (gid >= total) return;
  int cf = gid % DIN;            // c*FEAT + f
  int c  = cf >> 9;              // /512
  float4 xv = ((const float4*)x)[gid];
  float4 wv = ((const float4*)W1)[c];
  float v = xv.x * wv.x + xv.y * wv.y + xv.z * wv.z + xv.w * wv.w + b1[c];
  out[gid] = f2bf(v);
}

// ---------------------------------------------------------------------------
// Kernel 2: transpose + cast fp32 [R, Ncol] -> bf16 [Ncol, R]
// ---------------------------------------------------------------------------
__global__ __launch_bounds__(256) void transpose_cast(
    const float* __restrict__ in, unsigned short* __restrict__ out,
    int R, int Ncol)
{
  __shared__ float tile[32][33];
  int bx = blockIdx.x * 32;      // col base (Ncol dim)
  int by = blockIdx.y * 32;      // row base (R dim)
  int tx = threadIdx.x, ty = threadIdx.y;   // (32, 8)
  #pragma unroll
  for (int i = 0; i < 32; i += 8)
    tile[ty + i][tx] = in[(size_t)(by + ty + i) * Ncol + bx + tx];
  __syncthreads();
  #pragma unroll
  for (int i = 0; i < 32; i += 8)
    out[(size_t)(bx + ty + i) * R + by + tx] = f2bf(tile[tx][ty + i]);
}

// ---------------------------------------------------------------------------
// Kernel 3: GEMM1 with split-K=2.  A [M,K] bf16 row-major, BT [N,K] bf16.
// 128x128 tile, BK=32, 256 threads = 4 waves (2x2 of 64x64), m97 structure.
// Writes fp32 partials Cp[splitk][M][N].
// ---------------------------------------------------------------------------
#define G1_BM 128
#define G1_BN 128
#define G1_BK 32
#define SPLITK 2

__global__ __launch_bounds__(256, 2) void gemm1_kernel(
    const unsigned short* __restrict__ A,   // [M,K]
    const unsigned short* __restrict__ BT,  // [N,K]
    float* __restrict__ Cp,                 // [SPLITK, M, N]
    int M, int N, int K)
{
  __shared__ unsigned short As[G1_BM * G1_BK];   // 8 KB
  __shared__ unsigned short Bs[G1_BN * G1_BK];   // 8 KB
  const int t    = threadIdx.x;
  const int lane = t & 63;
  const int wave = t >> 6;
  const int m0 = blockIdx.y * G1_BM;
  const int n0 = blockIdx.x * G1_BN;
  const int Ks = K / SPLITK;
  const int kbeg = blockIdx.z * Ks;

  const int wm = (wave >> 1) * 64;
  const int wn = (wave & 1) * 64;
  const int lm = lane & 15;
  const int lk = (lane >> 4) * 8;

  f32x4 acc[4][4];
  #pragma unroll
  for (int i = 0; i < 4; i++)
    #pragma unroll
    for (int j = 0; j < 4; j++) {
      f32x4 z = {0.f, 0.f, 0.f, 0.f};
      acc[i][j] = z;
    }

  const unsigned short* Ag = A  + (size_t)m0 * K + kbeg;
  const unsigned short* Bg = BT + (size_t)n0 * K + kbeg;

  for (int kk = 0; kk < Ks; kk += G1_BK) {
    // stage A tile: 128x32 bf16 = 8192 B = 2 rounds x 256 lanes x 16 B
    #pragma unroll
    for (int r = 0; r < 2; ++r) {
      int chunk = r * 256 + t;
      int row = chunk >> 2;
      int kc  = (chunk & 3) * 8;
      async_copy16(Ag + (size_t)row * K + kk + kc, As + chunk * 8);
    }
    #pragma unroll
    for (int r = 0; r < 2; ++r) {
      int chunk = r * 256 + t;
      int row = chunk >> 2;
      int kc  = (chunk & 3) * 8;
      async_copy16(Bg + (size_t)row * K + kk + kc, Bs + chunk * 8);
    }
    __syncthreads();

    bf16x8 af[4], bfr[4];
    #pragma unroll
    for (int i = 0; i < 4; i++)
      af[i] = *(const bf16x8*)(As + (wm + i * 16 + lm) * G1_BK + lk);
    #pragma unroll
    for (int j = 0; j < 4; j++)
      bfr[j] = *(const bf16x8*)(Bs + (wn + j * 16 + lm) * G1_BK + lk);
    #pragma unroll
    for (int i = 0; i < 4; i++)
      #pragma unroll
      for (int j = 0; j < 4; j++)
        acc[i][j] = __builtin_amdgcn_mfma_f32_16x16x32_bf16(af[i], bfr[j], acc[i][j], 0, 0, 0);
    __syncthreads();
  }

  // epilogue: fp32 partials. C/D layout: col=lane&15, row=(lane>>4)*4+reg
  float* Co = Cp + (size_t)blockIdx.z * M * N;
  const int rbase = (lane >> 4) * 4;
  #pragma unroll
  for (int i = 0; i < 4; i++)
    #pragma unroll
    for (int j = 0; j < 4; j++) {
      int col = n0 + wn + j * 16 + lm;
      #pragma unroll
      for (int r = 0; r < 4; r++) {
        int row = m0 + wm + i * 16 + rbase + r;
        Co[(size_t)row * N + col] = acc[i][j][r];
      }
    }
}

// ---------------------------------------------------------------------------
// Kernel 4: split-K reduce + bias + ReLU -> H bf16 [M, HIDDEN]
// ---------------------------------------------------------------------------
__global__ __launch_bounds__(256) void reduce_bias_relu(
    const float* __restrict__ Cp, const float* __restrict__ b2,
    unsigned short* __restrict__ H)
{
  const int MN = BATCH * HIDDEN;
  int i4 = blockIdx.x * 256 + threadIdx.x;        // float4 index
  if (i4 >= MN / 4) return;
  float4 a = ((const float4*)Cp)[i4];
  float4 b = ((const float4*)(Cp + MN))[i4];
  int col = (i4 * 4) & (HIDDEN - 1);
  float4 bb = *(const float4*)(b2 + col);
  ushort4 o;
  o.x = f2bf(fmaxf(a.x + b.x + bb.x, 0.f));
  o.y = f2bf(fmaxf(a.y + b.y + bb.y, 0.f));
  o.z = f2bf(fmaxf(a.z + b.z + bb.z, 0.f));
  o.w = f2bf(fmaxf(a.w + b.w + bb.w, 0.f));
  ((ushort4*)H)[i4] = o;
}

// ---------------------------------------------------------------------------
// Kernel 5: GEMM2.  H [M,1024] bf16 @ W3T [256,1024] bf16 + b3 -> out fp32.
// 64x64 tile, BK=32, 4 waves of 32x32.
// ---------------------------------------------------------------------------
__global__ __launch_bounds__(256, 2) void gemm2_kernel(
    const unsigned short* __restrict__ A,   // [M, K]
    const unsigned short* __restrict__ BT,  // [N, K]
    const float* __restrict__ b3,
    float* __restrict__ out)                // [M, N]
{
  const int M = BATCH, N = OUTPUT, K = HIDDEN;
  __shared__ unsigned short As[64 * 32];   // 4 KB
  __shared__ unsigned short Bs[64 * 32];   // 4 KB
  const int t    = threadIdx.x;
  const int lane = t & 63;
  const int wave = t >> 6;
  const int m0 = blockIdx.y * 64;
  const int n0 = blockIdx.x * 64;
  const int wm = (wave >> 1) * 32;
  const int wn = (wave & 1) * 32;
  const int lm = lane & 15;
  const int lk = (lane >> 4) * 8;
  const int row = t >> 2;
  const int kc  = (t & 3) * 8;

  f32x4 acc[2][2];
  #pragma unroll
  for (int i = 0; i < 2; i++)
    #pragma unroll
    for (int j = 0; j < 2; j++) {
      f32x4 z = {0.f, 0.f, 0.f, 0.f};
      acc[i][j] = z;
    }

  const unsigned short* Ag = A  + (size_t)m0 * K;
  const unsigned short* Bg = BT + (size_t)n0 * K;

  for (int kk = 0; kk < K; kk += 32) {
    async_copy16(Ag + (size_t)row * K + kk + kc, As + t * 8);
    async_copy16(Bg + (size_t)row * K + kk + kc, Bs + t * 8);
    __syncthreads();
    bf16x8 af[2], bfr[2];
    #pragma unroll
    for (int i = 0; i < 2; i++)
      af[i] = *(const bf16x8*)(As + (wm + i * 16 + lm) * 32 + lk);
    #pragma unroll
    for (int j = 0; j < 2; j++)
      bfr[j] = *(const bf16x8*)(Bs + (wn + j * 16 + lm) * 32 + lk);
    #pragma unroll
    for (int i = 0; i < 2; i++)
      #pragma unroll
      for (int j = 0; j < 2; j++)
        acc[i][j] = __builtin_amdgcn_mfma_f32_16x16x32_bf16(af[i], bfr[j], acc[i][j], 0, 0, 0);
    __syncthreads();
  }

  const int rbase = (lane >> 4) * 4;
  #pragma unroll
  for (int i = 0; i < 2; i++)
    #pragma unroll
    for (int j = 0; j < 2; j++) {
      int col = n0 + wn + j * 16 + lm;
      float bias = b3[col];
      #pragma unroll
      for (int r = 0; r < 4; r++) {
        int row_o = m0 + wm + i * 16 + rbase + r;
        out[(size_t)row_o * N + col] = acc[i][j][r] + bias;
      }
    }
}

// ---------------------------------------------------------------------------
extern "C" void kernel_launch(void* const* d_in, const int* in_sizes, int n_in,
                              void* d_out, int out_size, void* d_ws, size_t ws_size,
                              hipStream_t stream)
{
  const float* x  = (const float*)d_in[0];
  const float* W1 = (const float*)d_in[1];
  const float* b1 = (const float*)d_in[2];
  const float* W2 = (const float*)d_in[3];
  const float* b2 = (const float*)d_in[4];
  const float* W3 = (const float*)d_in[5];
  const float* b3 = (const float*)d_in[6];
  float* out = (float*)d_out;

  char* ws = (char*)d_ws;
  unsigned short* flatA = (unsigned short*)ws; ws += (size_t)BATCH * DIN * 2;        // 25.2 MB
  unsigned short* W2T   = (unsigned short*)ws; ws += (size_t)HIDDEN * DIN * 2;       // 12.6 MB
  unsigned short* W3T   = (unsigned short*)ws; ws += (size_t)OUTPUT * HIDDEN * 2;    // 0.5 MB
  float*          Cpart = (float*)ws;          ws += (size_t)SPLITK * BATCH * HIDDEN * 4; // 16.8 MB
  unsigned short* H     = (unsigned short*)ws; ws += (size_t)BATCH * HIDDEN * 2;     // 4.2 MB

  // 1. conv + cast (memory-bound streaming pass over x)
  conv_cast_kernel<<<(BATCH * DIN) / 256, 256, 0, stream>>>(x, W1, b1, flatA);
  // 2. weight transpose-casts
  transpose_cast<<<dim3(HIDDEN / 32, DIN / 32), dim3(32, 8), 0, stream>>>(W2, W2T, DIN, HIDDEN);
  transpose_cast<<<dim3(OUTPUT / 32, HIDDEN / 32), dim3(32, 8), 0, stream>>>(W3, W3T, HIDDEN, OUTPUT);
  // 3. GEMM1 split-K=2: grid 8 x 16 x 2 = 256 blocks
  gemm1_kernel<<<dim3(HIDDEN / G1_BN, BATCH / G1_BM, SPLITK), 256, 0, stream>>>(
      flatA, W2T, Cpart, BATCH, HIDDEN, DIN);
  // 4. reduce + bias + relu
  reduce_bias_relu<<<(BATCH * HIDDEN / 4) / 256, 256, 0, stream>>>(Cpart, b2, H);
  // 5. GEMM2: grid 4 x 32 = 128 blocks
  gemm2_kernel<<<dim3(OUTPUT / 64, BATCH / 64), 256, 0, stream>>>(H, W3T, b3, out);
}

// Round 2
// 360.291 us; speedup vs baseline: 1.0610x; 1.0610x over previous
//
#include <hip/hip_runtime.h>
#include <hip/hip_bf16.h>

// Problem constants
#define BATCH   2048
#define IN_CH   12
#define UPLAG   2048
#define STEP    4
#define FEAT    512              // UPLAG/STEP
#define DIN     6144             // IN_CH*FEAT
#define HIDDEN  1024
#define OUTPUT  256

typedef __bf16 bf16x8 __attribute__((ext_vector_type(8)));
typedef float  f32x4  __attribute__((ext_vector_type(4)));

__device__ __forceinline__ unsigned short f2bf(float f) {
  unsigned int u = __builtin_bit_cast(unsigned int, f);
  unsigned int r = (u + 0x7fffu + ((u >> 16) & 1u)) >> 16;   // RNE
  return (unsigned short)r;
}

__device__ __forceinline__ void async_copy16(const unsigned short* g, unsigned short* l) {
  __builtin_amdgcn_global_load_lds(
      (const __attribute__((address_space(1))) unsigned int*)g,
      (__attribute__((address_space(3))) unsigned int*)l, 16, 0, 0);
}

// ---------------------------------------------------------------------------
// Kernel 1: per-channel stride-4 conv + bias, cast to bf16.
// x: [B, C, L] fp32 viewed as float4 [B*C*F]; out flat: [B, C*F] bf16
// ---------------------------------------------------------------------------
__global__ __launch_bounds__(256) void conv_cast_kernel(
    const float* __restrict__ x, const float* __restrict__ W1,
    const float* __restrict__ b1, unsigned short* __restrict__ out)
{
  int gid = blockIdx.x * 256 + threadIdx.x;
  const int total = BATCH * DIN;
  if (gid >= total) return;
  int cf = gid % DIN;            // c*FEAT + f
  int c  = cf >> 9;              // /512
  float4 xv = ((const float4*)x)[gid];
  float4 wv = ((const float4*)W1)[c];
  float v = xv.x * wv.x + xv.y * wv.y + xv.z * wv.z + xv.w * wv.w + b1[c];
  out[gid] = f2bf(v);
}

// ---------------------------------------------------------------------------
// Kernel 2: transpose + cast fp32 [R, Ncol] -> bf16 [Ncol, R]
// ---------------------------------------------------------------------------
__global__ __launch_bounds__(256) void transpose_cast(
    const float* __restrict__ in, unsigned short* __restrict__ out,
    int R, int Ncol)
{
  __shared__ float tile[32][33];
  int bx = blockIdx.x * 32;      // col base (Ncol dim)
  int by = blockIdx.y * 32;      // row base (R dim)
  int tx = threadIdx.x, ty = threadIdx.y;   // (32, 8)
  #pragma unroll
  for (int i = 0; i < 32; i += 8)
    tile[ty + i][tx] = in[(size_t)(by + ty + i) * Ncol + bx + tx];
  __syncthreads();
  #pragma unroll
  for (int i = 0; i < 32; i += 8)
    out[(size_t)(bx + ty + i) * R + by + tx] = f2bf(tile[tx][ty + i]);
}

// ---------------------------------------------------------------------------
// Kernel 3: GEMM1 with split-K=6 (3 blocks/CU).  A [M,K] bf16, BT [N,K] bf16.
// 128x128 tile, BK=32, 256 threads = 4 waves (2x2 of 64x64).
// Writes fp32 partials Cp[splitk][M][N].
// ---------------------------------------------------------------------------
#define G1_BM 128
#define G1_BN 128
#define G1_BK 32
#define SPLITK 6

__global__ __launch_bounds__(256, 2) void gemm1_kernel(
    const unsigned short* __restrict__ A,   // [M,K]
    const unsigned short* __restrict__ BT,  // [N,K]
    float* __restrict__ Cp,                 // [SPLITK, M, N]
    int M, int N, int K)
{
  __shared__ unsigned short As[G1_BM * G1_BK];   // 8 KB
  __shared__ unsigned short Bs[G1_BN * G1_BK];   // 8 KB
  const int t    = threadIdx.x;
  const int lane = t & 63;
  const int wave = t >> 6;
  const int m0 = blockIdx.y * G1_BM;
  const int n0 = blockIdx.x * G1_BN;
  const int Ks = K / SPLITK;
  const int kbeg = blockIdx.z * Ks;

  const int wm = (wave >> 1) * 64;
  const int wn = (wave & 1) * 64;
  const int lm = lane & 15;
  const int lk = (lane >> 4) * 8;

  f32x4 acc[4][4];
  #pragma unroll
  for (int i = 0; i < 4; i++)
    #pragma unroll
    for (int j = 0; j < 4; j++) {
      f32x4 z = {0.f, 0.f, 0.f, 0.f};
      acc[i][j] = z;
    }

  const unsigned short* Ag = A  + (size_t)m0 * K + kbeg;
  const unsigned short* Bg = BT + (size_t)n0 * K + kbeg;

  for (int kk = 0; kk < Ks; kk += G1_BK) {
    #pragma unroll
    for (int r = 0; r < 2; ++r) {
      int chunk = r * 256 + t;
      int row = chunk >> 2;
      int kc  = (chunk & 3) * 8;
      async_copy16(Ag + (size_t)row * K + kk + kc, As + chunk * 8);
    }
    #pragma unroll
    for (int r = 0; r < 2; ++r) {
      int chunk = r * 256 + t;
      int row = chunk >> 2;
      int kc  = (chunk & 3) * 8;
      async_copy16(Bg + (size_t)row * K + kk + kc, Bs + chunk * 8);
    }
    __syncthreads();

    bf16x8 af[4], bfr[4];
    #pragma unroll
    for (int i = 0; i < 4; i++)
      af[i] = *(const bf16x8*)(As + (wm + i * 16 + lm) * G1_BK + lk);
    #pragma unroll
    for (int j = 0; j < 4; j++)
      bfr[j] = *(const bf16x8*)(Bs + (wn + j * 16 + lm) * G1_BK + lk);
    #pragma unroll
    for (int i = 0; i < 4; i++)
      #pragma unroll
      for (int j = 0; j < 4; j++)
        acc[i][j] = __builtin_amdgcn_mfma_f32_16x16x32_bf16(af[i], bfr[j], acc[i][j], 0, 0, 0);
    __syncthreads();
  }

  // epilogue: fp32 partials. C/D layout: col=lane&15, row=(lane>>4)*4+reg
  float* Co = Cp + (size_t)blockIdx.z * M * N;
  const int rbase = (lane >> 4) * 4;
  #pragma unroll
  for (int i = 0; i < 4; i++)
    #pragma unroll
    for (int j = 0; j < 4; j++) {
      int col = n0 + wn + j * 16 + lm;
      #pragma unroll
      for (int r = 0; r < 4; r++) {
        int row = m0 + wm + i * 16 + rbase + r;
        Co[(size_t)row * N + col] = acc[i][j][r];
      }
    }
}

// ---------------------------------------------------------------------------
// Kernel 4: split-K reduce + bias + ReLU -> H bf16 [M, HIDDEN]
// ---------------------------------------------------------------------------
__global__ __launch_bounds__(256) void reduce_bias_relu(
    const float* __restrict__ Cp, const float* __restrict__ b2,
    unsigned short* __restrict__ H)
{
  const int MN = BATCH * HIDDEN;
  int i4 = blockIdx.x * 256 + threadIdx.x;        // float4 index
  if (i4 >= MN / 4) return;
  float4 s = ((const float4*)Cp)[i4];
  #pragma unroll
  for (int p = 1; p < SPLITK; ++p) {
    float4 a = ((const float4*)(Cp + (size_t)p * MN))[i4];
    s.x += a.x; s.y += a.y; s.z += a.z; s.w += a.w;
  }
  int col = (i4 * 4) & (HIDDEN - 1);
  float4 bb = *(const float4*)(b2 + col);
  ushort4 o;
  o.x = f2bf(fmaxf(s.x + bb.x, 0.f));
  o.y = f2bf(fmaxf(s.y + bb.y, 0.f));
  o.z = f2bf(fmaxf(s.z + bb.z, 0.f));
  o.w = f2bf(fmaxf(s.w + bb.w, 0.f));
  ((ushort4*)H)[i4] = o;
}

// ---------------------------------------------------------------------------
// Kernel 5: GEMM2 split-K=4.  H [M,1024] bf16 @ W3T [256,1024] bf16 -> partials.
// 64x64 tile, BK=32, 4 waves of 32x32.
// ---------------------------------------------------------------------------
#define SPLITK2 4

__global__ __launch_bounds__(256, 2) void gemm2_kernel(
    const unsigned short* __restrict__ A,   // [M, K]
    const unsigned short* __restrict__ BT,  // [N, K]
    float* __restrict__ Cp)                 // [SPLITK2, M, N]
{
  const int M = BATCH, N = OUTPUT, K = HIDDEN;
  __shared__ unsigned short As[64 * 32];   // 4 KB
  __shared__ unsigned short Bs[64 * 32];   // 4 KB
  const int t    = threadIdx.x;
  const int lane = t & 63;
  const int wave = t >> 6;
  const int m0 = blockIdx.y * 64;
  const int n0 = blockIdx.x * 64;
  const int Ks = K / SPLITK2;
  const int kbeg = blockIdx.z * Ks;
  const int wm = (wave >> 1) * 32;
  const int wn = (wave & 1) * 32;
  const int lm = lane & 15;
  const int lk = (lane >> 4) * 8;
  const int row = t >> 2;
  const int kc  = (t & 3) * 8;

  f32x4 acc[2][2];
  #pragma unroll
  for (int i = 0; i < 2; i++)
    #pragma unroll
    for (int j = 0; j < 2; j++) {
      f32x4 z = {0.f, 0.f, 0.f, 0.f};
      acc[i][j] = z;
    }

  const unsigned short* Ag = A  + (size_t)m0 * K + kbeg;
  const unsigned short* Bg = BT + (size_t)n0 * K + kbeg;

  for (int kk = 0; kk < Ks; kk += 32) {
    async_copy16(Ag + (size_t)row * K + kk + kc, As + t * 8);
    async_copy16(Bg + (size_t)row * K + kk + kc, Bs + t * 8);
    __syncthreads();
    bf16x8 af[2], bfr[2];
    #pragma unroll
    for (int i = 0; i < 2; i++)
      af[i] = *(const bf16x8*)(As + (wm + i * 16 + lm) * 32 + lk);
    #pragma unroll
    for (int j = 0; j < 2; j++)
      bfr[j] = *(const bf16x8*)(Bs + (wn + j * 16 + lm) * 32 + lk);
    #pragma unroll
    for (int i = 0; i < 2; i++)
      #pragma unroll
      for (int j = 0; j < 2; j++)
        acc[i][j] = __builtin_amdgcn_mfma_f32_16x16x32_bf16(af[i], bfr[j], acc[i][j], 0, 0, 0);
    __syncthreads();
  }

  float* Co = Cp + (size_t)blockIdx.z * M * N;
  const int rbase = (lane >> 4) * 4;
  #pragma unroll
  for (int i = 0; i < 2; i++)
    #pragma unroll
    for (int j = 0; j < 2; j++) {
      int col = n0 + wn + j * 16 + lm;
      #pragma unroll
      for (int r = 0; r < 4; r++) {
        int row_o = m0 + wm + i * 16 + rbase + r;
        Co[(size_t)row_o * N + col] = acc[i][j][r];
      }
    }
}

// ---------------------------------------------------------------------------
// Kernel 6: GEMM2 split-K reduce + bias -> out fp32 [M, OUTPUT]
// ---------------------------------------------------------------------------
__global__ __launch_bounds__(256) void reduce2_bias(
    const float* __restrict__ Cp, const float* __restrict__ b3,
    float* __restrict__ out)
{
  const int MN = BATCH * OUTPUT;
  int i4 = blockIdx.x * 256 + threadIdx.x;
  if (i4 >= MN / 4) return;
  float4 s = ((const float4*)Cp)[i4];
  #pragma unroll
  for (int p = 1; p < SPLITK2; ++p) {
    float4 a = ((const float4*)(Cp + (size_t)p * MN))[i4];
    s.x += a.x; s.y += a.y; s.z += a.z; s.w += a.w;
  }
  int col = (i4 * 4) & (OUTPUT - 1);
  float4 bb = *(const float4*)(b3 + col);
  float4 o = {s.x + bb.x, s.y + bb.y, s.z + bb.z, s.w + bb.w};
  ((float4*)out)[i4] = o;
}

// ---------------------------------------------------------------------------
extern "C" void kernel_launch(void* const* d_in, const int* in_sizes, int n_in,
                              void* d_out, int out_size, void* d_ws, size_t ws_size,
                              hipStream_t stream)
{
  const float* x  = (const float*)d_in[0];
  const float* W1 = (const float*)d_in[1];
  const float* b1 = (const float*)d_in[2];
  const float* W2 = (const float*)d_in[3];
  const float* b2 = (const float*)d_in[4];
  const float* W3 = (const float*)d_in[5];
  const float* b3 = (const float*)d_in[6];
  float* out = (float*)d_out;

  char* ws = (char*)d_ws;
  unsigned short* flatA = (unsigned short*)ws; ws += (size_t)BATCH * DIN * 2;        // 25.2 MB
  unsigned short* W2T   = (unsigned short*)ws; ws += (size_t)HIDDEN * DIN * 2;       // 12.6 MB
  unsigned short* W3T   = (unsigned short*)ws; ws += (size_t)OUTPUT * HIDDEN * 2;    // 0.5 MB
  float*          Cpart = (float*)ws;          ws += (size_t)SPLITK * BATCH * HIDDEN * 4;  // 50.3 MB
  unsigned short* H     = (unsigned short*)ws; ws += (size_t)BATCH * HIDDEN * 2;     // 4.2 MB
  float*          Cp2   = (float*)ws;          ws += (size_t)SPLITK2 * BATCH * OUTPUT * 4; // 8.4 MB

  // 1. conv + cast (memory-bound streaming pass over x)
  conv_cast_kernel<<<(BATCH * DIN) / 256, 256, 0, stream>>>(x, W1, b1, flatA);
  // 2. weight transpose-casts
  transpose_cast<<<dim3(HIDDEN / 32, DIN / 32), dim3(32, 8), 0, stream>>>(W2, W2T, DIN, HIDDEN);
  transpose_cast<<<dim3(OUTPUT / 32, HIDDEN / 32), dim3(32, 8), 0, stream>>>(W3, W3T, HIDDEN, OUTPUT);
  // 3. GEMM1 split-K=6: grid 8 x 16 x 6 = 768 blocks (3 blocks/CU)
  gemm1_kernel<<<dim3(HIDDEN / G1_BN, BATCH / G1_BM, SPLITK), 256, 0, stream>>>(
      flatA, W2T, Cpart, BATCH, HIDDEN, DIN);
  // 4. reduce + bias + relu
  reduce_bias_relu<<<(BATCH * HIDDEN / 4) / 256, 256, 0, stream>>>(Cpart, b2, H);
  // 5. GEMM2 split-K=4: grid 4 x 32 x 4 = 512 blocks (2 blocks/CU)
  gemm2_kernel<<<dim3(OUTPUT / 64, BATCH / 64, SPLITK2), 256, 0, stream>>>(H, W3T, Cp2);
  // 6. reduce + bias
  reduce2_bias<<<(BATCH * OUTPUT / 4) / 256, 256, 0, stream>>>(Cp2, b3, out);
}

// Round 3
// 350.372 us; speedup vs baseline: 1.0910x; 1.0283x over previous
//
#include <hip/hip_runtime.h>
#include <hip/hip_bf16.h>

// Problem constants
#define BATCH   2048
#define IN_CH   12
#define UPLAG   2048
#define STEP    4
#define FEAT    512              // UPLAG/STEP
#define DIN     6144             // IN_CH*FEAT
#define HIDDEN  1024
#define OUTPUT  256

typedef __bf16 bf16x8 __attribute__((ext_vector_type(8)));
typedef float  f32x4  __attribute__((ext_vector_type(4)));

__device__ __forceinline__ unsigned short f2bf(float f) {
  unsigned int u = __builtin_bit_cast(unsigned int, f);
  unsigned int r = (u + 0x7fffu + ((u >> 16) & 1u)) >> 16;   // RNE
  return (unsigned short)r;
}

__device__ __forceinline__ float bf2f(unsigned short h) {
  unsigned int u = ((unsigned int)h) << 16;
  return __builtin_bit_cast(float, u);
}

__device__ __forceinline__ void async_copy16(const unsigned short* g, unsigned short* l) {
  __builtin_amdgcn_global_load_lds(
      (const __attribute__((address_space(1))) unsigned int*)g,
      (__attribute__((address_space(3))) unsigned int*)l, 16, 0, 0);
}

// ---------------------------------------------------------------------------
// Kernel 1: per-channel stride-4 conv + bias, cast to bf16.
// ---------------------------------------------------------------------------
__global__ __launch_bounds__(256) void conv_cast_kernel(
    const float* __restrict__ x, const float* __restrict__ W1,
    const float* __restrict__ b1, unsigned short* __restrict__ out)
{
  int gid = blockIdx.x * 256 + threadIdx.x;
  const int total = BATCH * DIN;
  if (gid >= total) return;
  int cf = gid % DIN;            // c*FEAT + f
  int c  = cf >> 9;              // /512
  float4 xv = ((const float4*)x)[gid];
  float4 wv = ((const float4*)W1)[c];
  float v = xv.x * wv.x + xv.y * wv.y + xv.z * wv.z + xv.w * wv.w + b1[c];
  out[gid] = f2bf(v);
}

// ---------------------------------------------------------------------------
// Kernel 2: transpose + cast fp32 [R, Ncol] -> bf16 [Ncol, R]
// ---------------------------------------------------------------------------
__global__ __launch_bounds__(256) void transpose_cast(
    const float* __restrict__ in, unsigned short* __restrict__ out,
    int R, int Ncol)
{
  __shared__ float tile[32][33];
  int bx = blockIdx.x * 32;
  int by = blockIdx.y * 32;
  int tx = threadIdx.x, ty = threadIdx.y;   // (32, 8)
  #pragma unroll
  for (int i = 0; i < 32; i += 8)
    tile[ty + i][tx] = in[(size_t)(by + ty + i) * Ncol + bx + tx];
  __syncthreads();
  #pragma unroll
  for (int i = 0; i < 32; i += 8)
    out[(size_t)(bx + ty + i) * R + by + tx] = f2bf(tile[tx][ty + i]);
}

// ---------------------------------------------------------------------------
// Kernel 3: GEMM1, split-K=6, XCD-locality swizzle, bf16 partials.
// A [M,K] bf16, BT [N,K] bf16 -> Cp[SPLITK][M][N] bf16.
// 1-D grid of 768 blocks; decode so blocks with id%8==g (assumed XCD g) own
// M-tiles {2g, 2g+1}: per-XCD A working set 3.1 MB -> L2-resident; each A
// k-slice is read by exactly one XCD (A HBM traffic 201->25 MB).
// ---------------------------------------------------------------------------
#define G1_BM 128
#define G1_BN 128
#define G1_BK 32
#define SPLITK 6

__global__ __launch_bounds__(256, 2) void gemm1_kernel(
    const unsigned short* __restrict__ A,   // [M,K]
    const unsigned short* __restrict__ BT,  // [N,K]
    unsigned short* __restrict__ Cp,        // [SPLITK, M, N] bf16
    int M, int N, int K)
{
  __shared__ unsigned short As[G1_BM * G1_BK];   // 8 KB
  __shared__ unsigned short Bs[G1_BN * G1_BK];   // 8 KB
  const int t    = threadIdx.x;
  const int lane = t & 63;
  const int wave = t >> 6;

  // swizzle decode: b = ((z*2+ylow)*8 + x)*8 + xcdg ;  y = xcdg*2 + ylow
  int b    = blockIdx.x;
  int xcdg = b & 7;
  int rest = b >> 3;          // 0..95
  int xt   = rest & 7;        // n-tile 0..7
  int zz   = rest >> 3;       // 0..11
  int zt   = zz >> 1;         // k-slice 0..5
  int yt   = (xcdg << 1) | (zz & 1);  // m-tile 0..15

  const int m0 = yt * G1_BM;
  const int n0 = xt * G1_BN;
  const int Ks = K / SPLITK;
  const int kbeg = zt * Ks;

  const int wm = (wave >> 1) * 64;
  const int wn = (wave & 1) * 64;
  const int lm = lane & 15;
  const int lk = (lane >> 4) * 8;

  f32x4 acc[4][4];
  #pragma unroll
  for (int i = 0; i < 4; i++)
    #pragma unroll
    for (int j = 0; j < 4; j++) {
      f32x4 z = {0.f, 0.f, 0.f, 0.f};
      acc[i][j] = z;
    }

  const unsigned short* Ag = A  + (size_t)m0 * K + kbeg;
  const unsigned short* Bg = BT + (size_t)n0 * K + kbeg;

  for (int kk = 0; kk < Ks; kk += G1_BK) {
    #pragma unroll
    for (int r = 0; r < 2; ++r) {
      int chunk = r * 256 + t;
      int row = chunk >> 2;
      int kc  = (chunk & 3) * 8;
      async_copy16(Ag + (size_t)row * K + kk + kc, As + chunk * 8);
    }
    #pragma unroll
    for (int r = 0; r < 2; ++r) {
      int chunk = r * 256 + t;
      int row = chunk >> 2;
      int kc  = (chunk & 3) * 8;
      async_copy16(Bg + (size_t)row * K + kk + kc, Bs + chunk * 8);
    }
    __syncthreads();

    bf16x8 af[4], bfr[4];
    #pragma unroll
    for (int i = 0; i < 4; i++)
      af[i] = *(const bf16x8*)(As + (wm + i * 16 + lm) * G1_BK + lk);
    #pragma unroll
    for (int j = 0; j < 4; j++)
      bfr[j] = *(const bf16x8*)(Bs + (wn + j * 16 + lm) * G1_BK + lk);
    #pragma unroll
    for (int i = 0; i < 4; i++)
      #pragma unroll
      for (int j = 0; j < 4; j++)
        acc[i][j] = __builtin_amdgcn_mfma_f32_16x16x32_bf16(af[i], bfr[j], acc[i][j], 0, 0, 0);
    __syncthreads();
  }

  // epilogue: bf16 partials. C/D layout: col=lane&15, row=(lane>>4)*4+reg
  unsigned short* Co = Cp + (size_t)zt * M * N;
  const int rbase = (lane >> 4) * 4;
  #pragma unroll
  for (int i = 0; i < 4; i++)
    #pragma unroll
    for (int j = 0; j < 4; j++) {
      int col = n0 + wn + j * 16 + lm;
      #pragma unroll
      for (int r = 0; r < 4; r++) {
        int row = m0 + wm + i * 16 + rbase + r;
        Co[(size_t)row * N + col] = f2bf(acc[i][j][r]);
      }
    }
}

// ---------------------------------------------------------------------------
// Kernel 4: split-K reduce + bias + ReLU -> H bf16 [M, HIDDEN]
// ---------------------------------------------------------------------------
__global__ __launch_bounds__(256) void reduce_bias_relu(
    const unsigned short* __restrict__ Cp, const float* __restrict__ b2,
    unsigned short* __restrict__ H)
{
  const int MN = BATCH * HIDDEN;
  int i4 = blockIdx.x * 256 + threadIdx.x;        // x4 index
  if (i4 >= MN / 4) return;
  float4 s = {0.f, 0.f, 0.f, 0.f};
  #pragma unroll
  for (int p = 0; p < SPLITK; ++p) {
    ushort4 a = ((const ushort4*)(Cp + (size_t)p * MN))[i4];
    s.x += bf2f(a.x); s.y += bf2f(a.y); s.z += bf2f(a.z); s.w += bf2f(a.w);
  }
  int col = (i4 * 4) & (HIDDEN - 1);
  float4 bb = *(const float4*)(b2 + col);
  ushort4 o;
  o.x = f2bf(fmaxf(s.x + bb.x, 0.f));
  o.y = f2bf(fmaxf(s.y + bb.y, 0.f));
  o.z = f2bf(fmaxf(s.z + bb.z, 0.f));
  o.w = f2bf(fmaxf(s.w + bb.w, 0.f));
  ((ushort4*)H)[i4] = o;
}

// ---------------------------------------------------------------------------
// Kernel 5: GEMM2 split-K=4, bf16 partials.
// ---------------------------------------------------------------------------
#define SPLITK2 4

__global__ __launch_bounds__(256, 2) void gemm2_kernel(
    const unsigned short* __restrict__ A,   // [M, K]
    const unsigned short* __restrict__ BT,  // [N, K]
    unsigned short* __restrict__ Cp)        // [SPLITK2, M, N] bf16
{
  const int M = BATCH, N = OUTPUT, K = HIDDEN;
  __shared__ unsigned short As[64 * 32];   // 4 KB
  __shared__ unsigned short Bs[64 * 32];   // 4 KB
  const int t    = threadIdx.x;
  const int lane = t & 63;
  const int wave = t >> 6;
  const int m0 = blockIdx.y * 64;
  const int n0 = blockIdx.x * 64;
  const int Ks = K / SPLITK2;
  const int kbeg = blockIdx.z * Ks;
  const int wm = (wave >> 1) * 32;
  const int wn = (wave & 1) * 32;
  const int lm = lane & 15;
  const int lk = (lane >> 4) * 8;
  const int row = t >> 2;
  const int kc  = (t & 3) * 8;

  f32x4 acc[2][2];
  #pragma unroll
  for (int i = 0; i < 2; i++)
    #pragma unroll
    for (int j = 0; j < 2; j++) {
      f32x4 z = {0.f, 0.f, 0.f, 0.f};
      acc[i][j] = z;
    }

  const unsigned short* Ag = A  + (size_t)m0 * K + kbeg;
  const unsigned short* Bg = BT + (size_t)n0 * K + kbeg;

  for (int kk = 0; kk < Ks; kk += 32) {
    async_copy16(Ag + (size_t)row * K + kk + kc, As + t * 8);
    async_copy16(Bg + (size_t)row * K + kk + kc, Bs + t * 8);
    __syncthreads();
    bf16x8 af[2], bfr[2];
    #pragma unroll
    for (int i = 0; i < 2; i++)
      af[i] = *(const bf16x8*)(As + (wm + i * 16 + lm) * 32 + lk);
    #pragma unroll
    for (int j = 0; j < 2; j++)
      bfr[j] = *(const bf16x8*)(Bs + (wn + j * 16 + lm) * 32 + lk);
    #pragma unroll
    for (int i = 0; i < 2; i++)
      #pragma unroll
      for (int j = 0; j < 2; j++)
        acc[i][j] = __builtin_amdgcn_mfma_f32_16x16x32_bf16(af[i], bfr[j], acc[i][j], 0, 0, 0);
    __syncthreads();
  }

  unsigned short* Co = Cp + (size_t)blockIdx.z * M * N;
  const int rbase = (lane >> 4) * 4;
  #pragma unroll
  for (int i = 0; i < 2; i++)
    #pragma unroll
    for (int j = 0; j < 2; j++) {
      int col = n0 + wn + j * 16 + lm;
      #pragma unroll
      for (int r = 0; r < 4; r++) {
        int row_o = m0 + wm + i * 16 + rbase + r;
        Co[(size_t)row_o * N + col] = f2bf(acc[i][j][r]);
      }
    }
}

// ---------------------------------------------------------------------------
// Kernel 6: GEMM2 split-K reduce + bias -> out fp32 [M, OUTPUT]
// ---------------------------------------------------------------------------
__global__ __launch_bounds__(256) void reduce2_bias(
    const unsigned short* __restrict__ Cp, const float* __restrict__ b3,
    float* __restrict__ out)
{
  const int MN = BATCH * OUTPUT;
  int i4 = blockIdx.x * 256 + threadIdx.x;
  if (i4 >= MN / 4) return;
  float4 s = {0.f, 0.f, 0.f, 0.f};
  #pragma unroll
  for (int p = 0; p < SPLITK2; ++p) {
    ushort4 a = ((const ushort4*)(Cp + (size_t)p * MN))[i4];
    s.x += bf2f(a.x); s.y += bf2f(a.y); s.z += bf2f(a.z); s.w += bf2f(a.w);
  }
  int col = (i4 * 4) & (OUTPUT - 1);
  float4 bb = *(const float4*)(b3 + col);
  float4 o = {s.x + bb.x, s.y + bb.y, s.z + bb.z, s.w + bb.w};
  ((float4*)out)[i4] = o;
}

// ---------------------------------------------------------------------------
extern "C" void kernel_launch(void* const* d_in, const int* in_sizes, int n_in,
                              void* d_out, int out_size, void* d_ws, size_t ws_size,
                              hipStream_t stream)
{
  const float* x  = (const float*)d_in[0];
  const float* W1 = (const float*)d_in[1];
  const float* b1 = (const float*)d_in[2];
  const float* W2 = (const float*)d_in[3];
  const float* b2 = (const float*)d_in[4];
  const float* W3 = (const float*)d_in[5];
  const float* b3 = (const float*)d_in[6];
  float* out = (float*)d_out;

  char* ws = (char*)d_ws;
  unsigned short* flatA = (unsigned short*)ws; ws += (size_t)BATCH * DIN * 2;        // 25.2 MB
  unsigned short* W2T   = (unsigned short*)ws; ws += (size_t)HIDDEN * DIN * 2;       // 12.6 MB
  unsigned short* W3T   = (unsigned short*)ws; ws += (size_t)OUTPUT * HIDDEN * 2;    // 0.5 MB
  unsigned short* Cpart = (unsigned short*)ws; ws += (size_t)SPLITK * BATCH * HIDDEN * 2;  // 25.2 MB
  unsigned short* H     = (unsigned short*)ws; ws += (size_t)BATCH * HIDDEN * 2;     // 4.2 MB
  unsigned short* Cp2   = (unsigned short*)ws; ws += (size_t)SPLITK2 * BATCH * OUTPUT * 2; // 4.2 MB

  // 1. conv + cast (memory-bound streaming pass over x)
  conv_cast_kernel<<<(BATCH * DIN) / 256, 256, 0, stream>>>(x, W1, b1, flatA);
  // 2. weight transpose-casts
  transpose_cast<<<dim3(HIDDEN / 32, DIN / 32), dim3(32, 8), 0, stream>>>(W2, W2T, DIN, HIDDEN);
  transpose_cast<<<dim3(OUTPUT / 32, HIDDEN / 32), dim3(32, 8), 0, stream>>>(W3, W3T, HIDDEN, OUTPUT);
  // 3. GEMM1 split-K=6, XCD swizzle: 768 blocks 1-D (3 blocks/CU)
  gemm1_kernel<<<768, 256, 0, stream>>>(flatA, W2T, Cpart, BATCH, HIDDEN, DIN);
  // 4. reduce + bias + relu
  reduce_bias_relu<<<(BATCH * HIDDEN / 4) / 256, 256, 0, stream>>>(Cpart, b2, H);
  // 5. GEMM2 split-K=4: grid 4 x 32 x 4 = 512 blocks (2 blocks/CU)
  gemm2_kernel<<<dim3(OUTPUT / 64, BATCH / 64, SPLITK2), 256, 0, stream>>>(H, W3T, Cp2);
  // 6. reduce + bias
  reduce2_bias<<<(BATCH * OUTPUT / 4) / 256, 256, 0, stream>>>(Cp2, b3, out);
}